// Round 4
// baseline (442.217 us; speedup 1.0000x reference)
//
#include <hip/hip_runtime.h>
#include <hip/hip_bf16.h>
#include <math.h>

#define B_   16
#define S_   4096
#define DIN  1024
#define V_   512
#define FOUT 120

typedef __attribute__((ext_vector_type(8))) short bf16x8;
typedef __attribute__((ext_vector_type(4))) float f32x4;

__device__ const float CSCALE = 0.1f / (64.0f * 4096.0f);
__device__ const float EPSF = 1e-5f;

// fp32 -> bf16 RNE
__device__ inline unsigned short f2b(float f) {
  unsigned u = __builtin_bit_cast(unsigned, f);
  unsigned r = (u + 0x7FFFu + ((u >> 16) & 1u)) >> 16;
  return (unsigned short)r;
}

__device__ inline bf16x8 pack8(float4 a, float4 b) {
  bf16x8 r;
  r[0] = (short)f2b(a.x); r[1] = (short)f2b(a.y);
  r[2] = (short)f2b(a.z); r[3] = (short)f2b(a.w);
  r[4] = (short)f2b(b.x); r[5] = (short)f2b(b.y);
  r[6] = (short)f2b(b.z); r[7] = (short)f2b(b.w);
  return r;
}

// Wb[g][c][k] bf16, plain row-major (g in {q,k,v}, c=0..511, k=0..1023)
__global__ void msr_convw(const float* __restrict__ Wq, const float* __restrict__ Wk,
                          const float* __restrict__ Wv, unsigned short* __restrict__ Wb) {
  int u = blockIdx.x * 256 + threadIdx.x;   // 0..196607 ; u*8 = ((g*512+c)*1024 + k8)
  int g = u >> 16;
  int c = (u >> 7) & 511;
  int k8 = (u & 127) << 3;
  const float* W = (g == 0) ? Wq : (g == 1) ? Wk : Wv;
  const float* src = W + (size_t)c * DIN + k8;
  float4 a = *(const float4*)src;
  float4 b = *(const float4*)(src + 4);
  *(bf16x8*)(Wb + (size_t)u * 8) = pack8(a, b);
}

// lgkm-only barrier: A ds_write must drain, but global prefetches (B, X) stay in flight.
#define BAR asm volatile("s_waitcnt lgkmcnt(0)\n\ts_barrier" ::: "memory")

// Main: BM=128 x-tile, 384 vN (3 gemms x 128 ch), BK=32, 8 waves (2M x 4N).
// B: direct global->reg from L2-resident bf16 weights (no LDS, no barrier coupling).
// A: LDS dbuf 2x8KB, frag-major, reg-staged pack (T14).
__global__ __launch_bounds__(512, 2) void msr_main(
    const float* __restrict__ x, const unsigned short* __restrict__ Wb,
    float* __restrict__ outacc) {
  int bid = blockIdx.x;
  int swz = (bid & 7) * 256 + (bid >> 3);   // XCD swizzle: each XCD sees ONE ct -> B slice L2-resident
  int ct = swz >> 9;                        // 0..3
  int rt = swz & 511;                       // 0..511
  int r0 = rt << 7;

  __shared__ __align__(16) unsigned short As[2][4096];   // 2 x 8KB

  const int t = threadIdx.x;
  const int w = t >> 6, lane = t & 63;
  const int wm4 = (w >> 2) * 4;   // m-frag base (0 or 4)
  const int nf0 = (w & 3) * 2;    // n-frag base (0,2,4,6)

  // B fragment base: frag (g,nt) step k: pB + g*524288 + nt*16384 + k*32 (shorts)
  // lane l holds col = base + (l&15), k-octet (l>>4)*8  [round-2-verified B layout]
  const unsigned short* pB = Wb
      + (size_t)(ct * 128 + nf0 * 16 + (lane & 15)) * DIN + ((lane >> 4) << 3);

  // A loader: thread t -> row t>>2, k-octet t&3 ; frag-major dest [proven r2/r3]
  const int awoff = (w * 64 + (t & 3) * 16 + ((t >> 2) & 15)) * 8;
  const float* xbase = x + (size_t)(r0 + (t >> 2)) * DIN + (t & 3) * 8;

  f32x4 acc[3][4][2];
#pragma unroll
  for (int g = 0; g < 3; ++g)
#pragma unroll
    for (int m = 0; m < 4; ++m)
#pragma unroll
      for (int n = 0; n < 2; ++n) acc[g][m][n] = (f32x4){0.f, 0.f, 0.f, 0.f};

  bf16x8 bA[3][2], bB[3][2], afr[4];
  float4 xA0, xA1, xB0, xB1;

#define LOADB(dst, kk) { \
  _Pragma("unroll") for (int g = 0; g < 3; ++g) \
  _Pragma("unroll") for (int n = 0; n < 2; ++n) \
    dst[g][n] = *(const bf16x8*)(pB + (size_t)g * 524288 + n * 16384 + (kk) * 32); }

#define READA(c) { \
  _Pragma("unroll") for (int m = 0; m < 4; ++m) \
    afr[m] = *(const bf16x8*)(&As[c][((wm4 + m) * 64 + lane) * 8]); }

#define MFMAS(bsrc) { \
  __builtin_amdgcn_s_setprio(1); \
  _Pragma("unroll") for (int g = 0; g < 3; ++g) \
  _Pragma("unroll") for (int m = 0; m < 4; ++m) \
  _Pragma("unroll") for (int n = 0; n < 2; ++n) \
    acc[g][m][n] = __builtin_amdgcn_mfma_f32_16x16x32_bf16(afr[m], bsrc[g][n], acc[g][m][n], 0, 0, 0); \
  __builtin_amdgcn_s_setprio(0); }

  // ---- prologue ----
  { const float* p = xbase;      xA0 = *(const float4*)p; xA1 = *(const float4*)(p + 4); }
  LOADB(bA, 0);
  *(bf16x8*)(&As[0][awoff]) = pack8(xA0, xA1);
  { const float* p = xbase + 32; xB0 = *(const float4*)p; xB1 = *(const float4*)(p + 4); }
  BAR;

  // ---- steps 0..29, unrolled by 2 ----
#pragma unroll 1
  for (int i = 0; i < 15; ++i) {
    const int k = i * 2;
    // even step k (c=0): compute bA; prefetch bB=B(k+1); write As[1] from X(k+1)=xB; load xA=X(k+2)
    LOADB(bB, k + 1);
    READA(0);
    MFMAS(bA);
    *(bf16x8*)(&As[1][awoff]) = pack8(xB0, xB1);
    { const float* p = xbase + (k + 2) * 32; xA0 = *(const float4*)p; xA1 = *(const float4*)(p + 4); }
    BAR;
    // odd step k+1 (c=1): compute bB; prefetch bA=B(k+2); write As[0] from X(k+2)=xA; load xB=X(k+3)
    LOADB(bA, k + 2);
    READA(1);
    MFMAS(bB);
    *(bf16x8*)(&As[0][awoff]) = pack8(xA0, xA1);
    { const int kn = (i == 14) ? 31 : (k + 3);   // clamp: avoid OOB read at tail
      const float* p = xbase + kn * 32; xB0 = *(const float4*)p; xB1 = *(const float4*)(p + 4); }
    BAR;
  }
  // ---- step 30 (c=0) ----
  LOADB(bB, 31);
  READA(0);
  MFMAS(bA);
  *(bf16x8*)(&As[1][awoff]) = pack8(xB0, xB1);
  BAR;
  // ---- step 31 (c=1) ----
  READA(1);
  MFMAS(bB);

  // ---- epilogue: p = (q*k)[c^1] * v[c], fold rows, block-reduce [r3-verified] ----
  float pd0 = 0.f, pd1 = 0.f;
#pragma unroll
  for (int m = 0; m < 4; ++m)
#pragma unroll
    for (int r = 0; r < 4; ++r) {
      float qk0 = acc[0][m][0][r] * acc[1][m][0][r];
      float qk1 = acc[0][m][1][r] * acc[1][m][1][r];
      pd0 += __shfl_xor(qk0, 1, 64) * acc[2][m][0][r];
      pd1 += __shfl_xor(qk1, 1, 64) * acc[2][m][1][r];
    }
  pd0 += __shfl_xor(pd0, 16, 64); pd0 += __shfl_xor(pd0, 32, 64);
  pd1 += __shfl_xor(pd1, 16, 64); pd1 += __shfl_xor(pd1, 32, 64);

  float* red = (float*)&As[0][0];   // As[0] dead after step 30 barrier
  if (lane < 16) { red[w * 32 + lane] = pd0; red[w * 32 + 16 + lane] = pd1; }
  __syncthreads();
  if (t < 64) {
    int wn0 = t >> 5, idx = t & 31;
    float s = red[wn0 * 32 + idx] + red[(wn0 + 2) * 32 + idx] +
              red[(wn0 + 4) * 32 + idx] + red[(wn0 + 6) * 32 + idx];
    atomicAdd(&outacc[((rt >> 2) << 6) + t], s);
  }
#undef LOADB
#undef READA
#undef MFMAS
}

// Finish: per-batch RMSNorm -> exact gelu -> @ Wout.T
__global__ __launch_bounds__(256) void msr_finish(
    const float* __restrict__ outacc, const float* __restrict__ gamma,
    const float* __restrict__ Wout, float* __restrict__ y) {
  const int b = blockIdx.x;
  const int t = threadIdx.x;
  __shared__ float g[V_];
  __shared__ float wsum[4];

  float v0 = outacc[b * V_ + t] * CSCALE;
  float v1 = outacc[b * V_ + 256 + t] * CSCALE;
  float ss = v0 * v0 + v1 * v1;
#pragma unroll
  for (int o = 32; o > 0; o >>= 1) ss += __shfl_down(ss, o, 64);
  if ((t & 63) == 0) wsum[t >> 6] = ss;
  __syncthreads();
  float tot = wsum[0] + wsum[1] + wsum[2] + wsum[3];
  float rs = rsqrtf(tot * (1.0f / (float)V_) + EPSF);

  float r0v = v0 * rs * gamma[t];
  float r1v = v1 * rs * gamma[t + 256];
  g[t]       = 0.5f * r0v * (1.0f + erff(r0v * 0.70710678118654752f));
  g[t + 256] = 0.5f * r1v * (1.0f + erff(r1v * 0.70710678118654752f));
  __syncthreads();

  if (t < FOUT) {
    const float* wr = Wout + (size_t)t * V_;
    float acc = 0.f;
#pragma unroll 4
    for (int c = 0; c < V_; c += 4) {
      float4 w4 = *(const float4*)(wr + c);
      acc += g[c] * w4.x + g[c + 1] * w4.y + g[c + 2] * w4.z + g[c + 3] * w4.w;
    }
    y[b * FOUT + t] = acc;
  }
}

extern "C" void kernel_launch(void* const* d_in, const int* in_sizes, int n_in,
                              void* d_out, int out_size, void* d_ws, size_t ws_size,
                              hipStream_t stream) {
  const float* x     = (const float*)d_in[0];
  const float* Wq    = (const float*)d_in[1];
  const float* Wk    = (const float*)d_in[2];
  const float* Wv    = (const float*)d_in[3];
  const float* Wout  = (const float*)d_in[4];
  const float* gamma = (const float*)d_in[5];

  float* outacc = (float*)d_ws;                                  // 32 KB
  unsigned short* Wb = (unsigned short*)((char*)d_ws + 32768);   // 3 MB bf16 weights
  float* y = (float*)d_out;

  msr_convw<<<768, 256, 0, stream>>>(Wq, Wk, Wv, Wb);
  hipMemsetAsync(outacc, 0, B_ * V_ * sizeof(float), stream);
  msr_main<<<2048, 512, 0, stream>>>(x, Wb, outacc);
  msr_finish<<<B_, 256, 0, stream>>>(outacc, gamma, Wout, y);
}

// Round 5
// 352.210 us; speedup vs baseline: 1.2555x; 1.2555x over previous
//
#include <hip/hip_runtime.h>
#include <hip/hip_bf16.h>
#include <math.h>

#define B_   16
#define S_   4096
#define DIN  1024
#define V_   512
#define FOUT 120

typedef __attribute__((ext_vector_type(8))) short bf16x8;
typedef __attribute__((ext_vector_type(4))) float f32x4;

__device__ const float CSCALE = 0.1f / (64.0f * 4096.0f);
__device__ const float EPSF = 1e-5f;

// fp32 -> bf16 RNE
__device__ inline unsigned short f2b(float f) {
  unsigned u = __builtin_bit_cast(unsigned, f);
  unsigned r = (u + 0x7FFFu + ((u >> 16) & 1u)) >> 16;
  return (unsigned short)r;
}

__device__ inline bf16x8 pack8(float4 a, float4 b) {
  bf16x8 r;
  r[0] = (short)f2b(a.x); r[1] = (short)f2b(a.y);
  r[2] = (short)f2b(a.z); r[3] = (short)f2b(a.w);
  r[4] = (short)f2b(b.x); r[5] = (short)f2b(b.y);
  r[6] = (short)f2b(b.z); r[7] = (short)f2b(b.w);
  return r;
}

// Wb[g][c][k] bf16, plain row-major (g in {q,k,v}, c=0..511, k=0..1023)
__global__ void msr_convw(const float* __restrict__ Wq, const float* __restrict__ Wk,
                          const float* __restrict__ Wv, unsigned short* __restrict__ Wb) {
  int u = blockIdx.x * 256 + threadIdx.x;   // 0..196607 ; u*8 = ((g*512+c)*1024 + k8)
  int g = u >> 16;
  int c = (u >> 7) & 511;
  int k8 = (u & 127) << 3;
  const float* W = (g == 0) ? Wq : (g == 1) ? Wk : Wv;
  const float* src = W + (size_t)c * DIN + k8;
  float4 a = *(const float4*)src;
  float4 b = *(const float4*)(src + 4);
  *(bf16x8*)(Wb + (size_t)u * 8) = pack8(a, b);
}

// lgkm-only barrier: A ds-traffic drains; global B/X prefetches stay in flight.
#define BAR asm volatile("s_waitcnt lgkmcnt(0)\n\ts_barrier" ::: "memory")

// Main: 256 thr = 4 waves (2 blocks/CU => two independent barrier domains).
// Tile: M=128 rows x 64 channels x 3 gemms; BK=32, 32 steps.
// Wave w owns channels [ct*64 + w*16, +16) for ALL of q,k,v:
//   acc[g][m] (8 m-frags x 3 g) = 96 AGPR; B direct global->reg (L2-resident,
//   XCD-pinned by ct = bid&7); A via LDS dbuf 2x8KB.
__global__ __launch_bounds__(256, 2) void msr_main(
    const float* __restrict__ x, const unsigned short* __restrict__ Wb,
    float* __restrict__ outacc) {
  const int bid = blockIdx.x;
  const int ct = bid & 7;          // ct pinned to XCD (dispatch round-robin heuristic)
  const int rt = bid >> 3;         // 0..511
  const int r0 = rt << 7;

  __shared__ __align__(16) unsigned short As[2][4096];   // 2 x 8KB, frag-major

  const int t = threadIdx.x;
  const int w = t >> 6, lane = t & 63;

  // B fragment pointer: lane l -> col ct*64 + w*16 + (l&15), k-octet (l>>4)*8.
  // step k adds k*32 shorts; g adds 524288 shorts. [r2/r4-verified mapping]
  const unsigned short* pB =
      Wb + (size_t)(ct * 64 + w * 16 + (lane & 15)) * DIN + ((lane >> 4) << 3);

  // A loader: thread t -> row t>>1 (0..127), k-half ks = t&1 (k-octets 2ks, 2ks+1)
  const int row = t >> 1, ks = t & 1;
  const float* xbase = x + (size_t)(r0 + row) * DIN + ks * 16;
  const int aw0 = (((row >> 4) * 64) + (ks * 2) * 16 + (row & 15)) * 8;  // shorts

  f32x4 acc[3][8];
#pragma unroll
  for (int g = 0; g < 3; ++g)
#pragma unroll
    for (int m = 0; m < 8; ++m) acc[g][m] = (f32x4){0.f, 0.f, 0.f, 0.f};

  bf16x8 afr[8], bA[3], bB[3];
  float4 xA[4], xB[4];

#define LOADX(dst, kk) { const float* p = xbase + (kk) * 32; \
  dst[0] = *(const float4*)p;        dst[1] = *(const float4*)(p + 4); \
  dst[2] = *(const float4*)(p + 8);  dst[3] = *(const float4*)(p + 12); }

#define WRITEA(c, src) { \
  *(bf16x8*)(&As[c][aw0])       = pack8(src[0], src[1]); \
  *(bf16x8*)(&As[c][aw0 + 128]) = pack8(src[2], src[3]); }

#define LOADB(dst, kk) { \
  _Pragma("unroll") for (int g = 0; g < 3; ++g) \
    dst[g] = *(const bf16x8*)(pB + (size_t)g * 524288 + (kk) * 32); }

#define READA(c) { \
  _Pragma("unroll") for (int m = 0; m < 8; ++m) \
    afr[m] = *(const bf16x8*)(&As[c][(m * 64 + lane) * 8]); }

#define MFMAS(b) { \
  __builtin_amdgcn_s_setprio(1); \
  _Pragma("unroll") for (int g = 0; g < 3; ++g) \
  _Pragma("unroll") for (int m = 0; m < 8; ++m) \
    acc[g][m] = __builtin_amdgcn_mfma_f32_16x16x32_bf16(afr[m], b[g], acc[g][m], 0, 0, 0); \
  __builtin_amdgcn_s_setprio(0); }

  // ---- prologue ----
  LOADX(xA, 0);
  LOADB(bA, 0);
  WRITEA(0, xA);          // compiler waits vmcnt for xA before pack
  LOADX(xB, 1);
  BAR;

  // ---- steps 0..29, unrolled by 2 ----
#pragma unroll 1
  for (int i = 0; i < 15; ++i) {
    const int k = i * 2;
    // even step k (c=0)
    LOADB(bB, k + 1);
    READA(0);
    WRITEA(1, xB);
    LOADX(xA, k + 2);
    MFMAS(bA);
    BAR;
    // odd step k+1 (c=1)
    LOADB(bA, k + 2);
    READA(1);
    WRITEA(0, xA);
    LOADX(xB, k + 3);     // i=14 -> loads X(31), the last tile
    MFMAS(bB);
    BAR;
  }
  // ---- step 30 (c=0) ----
  LOADB(bB, 31);
  READA(0);
  WRITEA(1, xB);
  MFMAS(bA);
  BAR;
  // ---- step 31 (c=1) ----
  READA(1);
  MFMAS(bB);

  // ---- epilogue: p = (q*k)[c^1] * v[c]; fold rows; direct atomicAdd ----
  // C/D layout: col = lane&15 (channel), row = (lane>>4)*4 + r  [HW-verified r2]
  float pd = 0.f;
#pragma unroll
  for (int m = 0; m < 8; ++m)
#pragma unroll
    for (int r = 0; r < 4; ++r) {
      float qk = acc[0][m][r] * acc[1][m][r];
      pd += __shfl_xor(qk, 1, 64) * acc[2][m][r];
    }
  pd += __shfl_xor(pd, 16, 64);
  pd += __shfl_xor(pd, 32, 64);
  // wave w owns d = w*16 + (lane&15)  (ct*64 folds out mod 64); h-block = r0>>9
  if (lane < 16) atomicAdd(&outacc[((r0 >> 9) << 6) + w * 16 + lane], pd);
#undef LOADX
#undef WRITEA
#undef LOADB
#undef READA
#undef MFMAS
}

// Finish: per-batch RMSNorm -> exact gelu -> @ Wout.T
__global__ __launch_bounds__(256) void msr_finish(
    const float* __restrict__ outacc, const float* __restrict__ gamma,
    const float* __restrict__ Wout, float* __restrict__ y) {
  const int b = blockIdx.x;
  const int t = threadIdx.x;
  __shared__ float g[V_];
  __shared__ float wsum[4];

  float v0 = outacc[b * V_ + t] * CSCALE;
  float v1 = outacc[b * V_ + 256 + t] * CSCALE;
  float ss = v0 * v0 + v1 * v1;
#pragma unroll
  for (int o = 32; o > 0; o >>= 1) ss += __shfl_down(ss, o, 64);
  if ((t & 63) == 0) wsum[t >> 6] = ss;
  __syncthreads();
  float tot = wsum[0] + wsum[1] + wsum[2] + wsum[3];
  float rs = rsqrtf(tot * (1.0f / (float)V_) + EPSF);

  float r0v = v0 * rs * gamma[t];
  float r1v = v1 * rs * gamma[t + 256];
  g[t]       = 0.5f * r0v * (1.0f + erff(r0v * 0.70710678118654752f));
  g[t + 256] = 0.5f * r1v * (1.0f + erff(r1v * 0.70710678118654752f));
  __syncthreads();

  if (t < FOUT) {
    const float* wr = Wout + (size_t)t * V_;
    float acc = 0.f;
#pragma unroll 4
    for (int c = 0; c < V_; c += 4) {
      float4 w4 = *(const float4*)(wr + c);
      acc += g[c] * w4.x + g[c + 1] * w4.y + g[c + 2] * w4.z + g[c + 3] * w4.w;
    }
    y[b * FOUT + t] = acc;
  }
}

extern "C" void kernel_launch(void* const* d_in, const int* in_sizes, int n_in,
                              void* d_out, int out_size, void* d_ws, size_t ws_size,
                              hipStream_t stream) {
  const float* x     = (const float*)d_in[0];
  const float* Wq    = (const float*)d_in[1];
  const float* Wk    = (const float*)d_in[2];
  const float* Wv    = (const float*)d_in[3];
  const float* Wout  = (const float*)d_in[4];
  const float* gamma = (const float*)d_in[5];

  float* outacc = (float*)d_ws;                                  // 32 KB
  unsigned short* Wb = (unsigned short*)((char*)d_ws + 32768);   // 3 MB bf16 weights
  float* y = (float*)d_out;

  msr_convw<<<768, 256, 0, stream>>>(Wq, Wk, Wv, Wb);
  hipMemsetAsync(outacc, 0, B_ * V_ * sizeof(float), stream);
  msr_main<<<4096, 256, 0, stream>>>(x, Wb, outacc);
  msr_finish<<<B_, 256, 0, stream>>>(outacc, gamma, Wout, y);
}